// Round 1
// baseline (180.574 us; speedup 1.0000x reference)
//
#include <hip/hip_runtime.h>
#include <hip/hip_bf16.h>
#include <stdint.h>

// Problem constants
#define B_    2
#define S_    2048
#define H_    16
#define DH_   64
#define D_    1024
#define ND3   3072      // 3*D
#define MTOT  4096      // B*S

typedef __attribute__((ext_vector_type(8))) short bf16x8;
typedef __attribute__((ext_vector_type(4))) short bf16x4;
typedef __attribute__((ext_vector_type(4))) float f32x4;

__device__ inline short f2bs(float f) {
  __hip_bfloat16 h = __float2bfloat16(f);
  return *reinterpret_cast<short*>(&h);
}

__device__ inline void gl_lds16(const void* g, void* l) {
  __builtin_amdgcn_global_load_lds(
      (const __attribute__((address_space(1))) uint32_t*)g,
      (__attribute__((address_space(3))) uint32_t*)l, 16, 0, 0);
}

// ---------------------------------------------------------------- x -> bf16
__global__ __launch_bounds__(256) void xcast_kernel(const float* __restrict__ X,
                                                    short* __restrict__ Xb) {
  const int i = (blockIdx.x * 256 + threadIdx.x) * 4;
  float4 v = *reinterpret_cast<const float4*>(X + i);
  bf16x4 o;
  o[0] = f2bs(v.x); o[1] = f2bs(v.y); o[2] = f2bs(v.z); o[3] = f2bs(v.w);
  *reinterpret_cast<bf16x4*>(Xb + i) = o;
}

// ------------------------------------------- W[k][n] -> Wt[n][k] bf16 (x3)
__global__ __launch_bounds__(256) void wcast_kernel(const float* __restrict__ Wq,
                                                    const float* __restrict__ Wk,
                                                    const float* __restrict__ Wv,
                                                    short* __restrict__ Wt) {
  __shared__ float t[32][33];
  const float* W = blockIdx.z == 0 ? Wq : (blockIdx.z == 1 ? Wk : Wv);
  short* out = Wt + (size_t)blockIdx.z * (D_ * D_);
  const int x = threadIdx.x, y = threadIdx.y;
  const int n0 = blockIdx.x * 32, k0 = blockIdx.y * 32;
#pragma unroll
  for (int i = 0; i < 4; ++i)
    t[y + 8 * i][x] = W[(size_t)(k0 + y + 8 * i) * D_ + n0 + x];
  __syncthreads();
#pragma unroll
  for (int i = 0; i < 4; ++i)
    out[(size_t)(n0 + y + 8 * i) * D_ + k0 + x] = f2bs(t[x][y + 8 * i]);
}

// ---------------------------------------------------------------- QKV GEMM
// C[4096][3072] = Xb[4096][1024] @ W[1024][3072] (+bias, Q scaled by 0.125)
// Wt is the N-major (transposed) weight: Wt[n][k].
__global__ __launch_bounds__(256, 2) void qkv_gemm_kernel(
    const short* __restrict__ Xb, const short* __restrict__ Wt,
    const float* __restrict__ bq, const float* __restrict__ bk,
    const float* __restrict__ bv, short* __restrict__ QKV) {
  __shared__ short As[128 * 64];
  __shared__ short Bs[128 * 64];
  const int tid = threadIdx.x;
  const int lane = tid & 63, wid = tid >> 6;
  const int l15 = lane & 15, lg = lane >> 4;
  const int m0 = blockIdx.x * 128, n0 = blockIdx.y * 128;
  const int wr = (wid >> 1) * 64, wc = (wid & 1) * 64;

  f32x4 acc[4][4];
#pragma unroll
  for (int i = 0; i < 4; ++i)
#pragma unroll
    for (int j = 0; j < 4; ++j) acc[i][j] = (f32x4){0.f, 0.f, 0.f, 0.f};

  for (int k0 = 0; k0 < D_; k0 += 64) {
    __syncthreads();  // all waves done reading previous tiles
#pragma unroll
    for (int it = 0; it < 4; ++it) {
      const int e = (it * 256 + tid) * 8;      // element index in 128x64 tile
      const int row = e >> 6, kk = e & 63;
      const int lb = (it * 256 + (tid & 192)) * 16;  // wave-uniform LDS byte base
      gl_lds16(Xb + (size_t)(m0 + row) * D_ + k0 + kk, (char*)As + lb);
      gl_lds16(Wt + (size_t)(n0 + row) * D_ + k0 + kk, (char*)Bs + lb);
    }
    __syncthreads();  // drains vmcnt
#pragma unroll
    for (int ks = 0; ks < 2; ++ks) {
      bf16x8 a[4], b[4];
#pragma unroll
      for (int mt = 0; mt < 4; ++mt)
        a[mt] = *reinterpret_cast<const bf16x8*>(
            &As[(wr + mt * 16 + l15) * 64 + ks * 32 + lg * 8]);
#pragma unroll
      for (int nt = 0; nt < 4; ++nt)
        b[nt] = *reinterpret_cast<const bf16x8*>(
            &Bs[(wc + nt * 16 + l15) * 64 + ks * 32 + lg * 8]);
#pragma unroll
      for (int mt = 0; mt < 4; ++mt)
#pragma unroll
        for (int nt = 0; nt < 4; ++nt)
          acc[mt][nt] = __builtin_amdgcn_mfma_f32_16x16x32_bf16(
              a[mt], b[nt], acc[mt][nt], 0, 0, 0);
    }
  }
  // epilogue: bias + Q-scale + bf16 store
#pragma unroll
  for (int nt = 0; nt < 4; ++nt) {
    const int col = n0 + wc + nt * 16 + l15;
    float bias, qs;
    if (col < D_)            { bias = bq[col];          qs = 0.125f; }
    else if (col < 2 * D_)   { bias = bk[col - D_];     qs = 1.f; }
    else                     { bias = bv[col - 2 * D_]; qs = 1.f; }
#pragma unroll
    for (int mt = 0; mt < 4; ++mt)
#pragma unroll
      for (int r = 0; r < 4; ++r) {
        const int row = m0 + wr + mt * 16 + lg * 4 + r;
        QKV[(size_t)row * ND3 + col] = f2bs((acc[mt][nt][r] + bias) * qs);
      }
  }
}

// ----------------------------------------------------------- flash attention
// grid (S/64, B*H); block 256 (4 waves, 16 q-rows each). Causal.
__global__ __launch_bounds__(256, 2) void attn_kernel(
    const short* __restrict__ QKV, float* __restrict__ Out) {
  __shared__ short Ks[64][72];        // K tile, row-major [kv][dh], +8 pad
  __shared__ short Vt[64][72];        // V tile transposed [dh][kv], +8 pad
  __shared__ short Ps[4][16][72];     // per-wave P tile [q][kv], +8 pad
  const int tid = threadIdx.x;
  const int lane = tid & 63, wid = tid >> 6;
  const int l15 = lane & 15, lg = lane >> 4;
  const int qt = blockIdx.x;
  const int b = blockIdx.y >> 4, h = blockIdx.y & 15;
  const int q0 = qt * 64;
  const size_t rowbase = (size_t)b * S_ * ND3;
  const short* Qg = QKV + rowbase + h * DH_;
  const short* Kg = QKV + rowbase + D_ + h * DH_;
  const short* Vg = QKV + rowbase + 2 * D_ + h * DH_;

  // Q fragments, held in registers for the whole KV loop (pre-scaled by 1/8)
  bf16x8 qf[2];
  {
    const int qrow = q0 + wid * 16 + l15;
#pragma unroll
    for (int ks = 0; ks < 2; ++ks)
      qf[ks] = *reinterpret_cast<const bf16x8*>(Qg + (size_t)qrow * ND3 +
                                                ks * 32 + lg * 8);
  }

  f32x4 o[4];
#pragma unroll
  for (int i = 0; i < 4; ++i) o[i] = (f32x4){0.f, 0.f, 0.f, 0.f};
  float mrun[4] = {-1e30f, -1e30f, -1e30f, -1e30f};
  float lsum[4] = {0.f, 0.f, 0.f, 0.f};

  const int srow = tid & 63, scol = (tid >> 6) * 16;  // staging split

  for (int kvt = 0; kvt <= qt; ++kvt) {
    const int kv0 = kvt * 64;
    __syncthreads();
    {  // stage K row-major; V transposed
      const short* gk = Kg + (size_t)(kv0 + srow) * ND3 + scol;
      bf16x8 k0v = *reinterpret_cast<const bf16x8*>(gk);
      bf16x8 k1v = *reinterpret_cast<const bf16x8*>(gk + 8);
      *reinterpret_cast<bf16x8*>(&Ks[srow][scol]) = k0v;
      *reinterpret_cast<bf16x8*>(&Ks[srow][scol + 8]) = k1v;
      const short* gv = Vg + (size_t)(kv0 + srow) * ND3 + scol;
      bf16x8 v0v = *reinterpret_cast<const bf16x8*>(gv);
      bf16x8 v1v = *reinterpret_cast<const bf16x8*>(gv + 8);
#pragma unroll
      for (int i = 0; i < 8; ++i) Vt[scol + i][srow] = v0v[i];
#pragma unroll
      for (int i = 0; i < 8; ++i) Vt[scol + 8 + i][srow] = v1v[i];
    }
    __syncthreads();

    // S = Q K^T  (Q pre-scaled)
    f32x4 s[4];
#pragma unroll
    for (int i = 0; i < 4; ++i) s[i] = (f32x4){0.f, 0.f, 0.f, 0.f};
#pragma unroll
    for (int ks = 0; ks < 2; ++ks)
#pragma unroll
      for (int nt = 0; nt < 4; ++nt) {
        bf16x8 bfr = *reinterpret_cast<const bf16x8*>(
            &Ks[nt * 16 + l15][ks * 32 + lg * 8]);
        s[nt] = __builtin_amdgcn_mfma_f32_16x16x32_bf16(qf[ks], bfr, s[nt],
                                                        0, 0, 0);
      }
    if (kvt == qt) {  // diagonal tile: causal mask
#pragma unroll
      for (int nt = 0; nt < 4; ++nt) {
        const int col = kv0 + nt * 16 + l15;
#pragma unroll
        for (int r = 0; r < 4; ++r) {
          const int row = q0 + wid * 16 + lg * 4 + r;
          if (col > row) s[nt][r] = -1e30f;
        }
      }
    }
    // online softmax (rows live on 16-lane groups)
#pragma unroll
    for (int r = 0; r < 4; ++r) {
      float mx = fmaxf(fmaxf(s[0][r], s[1][r]), fmaxf(s[2][r], s[3][r]));
#pragma unroll
      for (int off = 1; off < 16; off <<= 1) mx = fmaxf(mx, __shfl_xor(mx, off));
      const float mnew = fmaxf(mrun[r], mx);
      const float sc = exp2f((mrun[r] - mnew) * 1.4426950408889634f);
      mrun[r] = mnew;
      float rowsum = 0.f;
#pragma unroll
      for (int nt = 0; nt < 4; ++nt) {
        float p = exp2f((s[nt][r] - mnew) * 1.4426950408889634f);
        s[nt][r] = p;
        rowsum += p;
      }
#pragma unroll
      for (int off = 1; off < 16; off <<= 1) rowsum += __shfl_xor(rowsum, off);
      lsum[r] = lsum[r] * sc + rowsum;
#pragma unroll
      for (int nt = 0; nt < 4; ++nt) o[nt][r] *= sc;
    }
    // P -> LDS (wave-local; DS ops in-order within a wave, no barrier needed)
#pragma unroll
    for (int nt = 0; nt < 4; ++nt)
#pragma unroll
      for (int r = 0; r < 4; ++r)
        Ps[wid][lg * 4 + r][nt * 16 + l15] = f2bs(s[nt][r]);
    // O += P V
#pragma unroll
    for (int ks = 0; ks < 2; ++ks) {
      bf16x8 af = *reinterpret_cast<const bf16x8*>(
          &Ps[wid][l15][ks * 32 + lg * 8]);
#pragma unroll
      for (int nt = 0; nt < 4; ++nt) {
        bf16x8 bfr = *reinterpret_cast<const bf16x8*>(
            &Vt[nt * 16 + l15][ks * 32 + lg * 8]);
        o[nt] = __builtin_amdgcn_mfma_f32_16x16x32_bf16(af, bfr, o[nt], 0, 0, 0);
      }
    }
  }
  // epilogue: O / lsum -> fp32 out [B,S,H,DH]
  const int orow0 = q0 + wid * 16 + lg * 4;
#pragma unroll
  for (int nt = 0; nt < 4; ++nt)
#pragma unroll
    for (int r = 0; r < 4; ++r)
      Out[((size_t)b * S_ + orow0 + r) * D_ + h * DH_ + nt * 16 + l15] =
          o[nt][r] / lsum[r];
}

// ---------------------------------------------------------------- launcher
extern "C" void kernel_launch(void* const* d_in, const int* in_sizes, int n_in,
                              void* d_out, int out_size, void* d_ws,
                              size_t ws_size, hipStream_t stream) {
  const float* x  = (const float*)d_in[0];
  const float* Wq = (const float*)d_in[1];
  const float* bq = (const float*)d_in[2];
  const float* Wk = (const float*)d_in[3];
  const float* bk = (const float*)d_in[4];
  const float* Wv = (const float*)d_in[5];
  const float* bv = (const float*)d_in[6];
  float* out = (float*)d_out;

  char* ws = (char*)d_ws;
  short* xb  = (short*)(ws);                         //  8 MB: [4096][1024] bf16
  short* Wt  = (short*)(ws + 8388608);               //  6 MB: [3072][1024] bf16
  short* qkv = (short*)(ws + 14680064);              // 24 MB: [4096][3072] bf16

  xcast_kernel<<<dim3(MTOT * D_ / (256 * 4)), dim3(256), 0, stream>>>(x, xb);
  wcast_kernel<<<dim3(32, 32, 3), dim3(32, 8), 0, stream>>>(Wq, Wk, Wv, Wt);
  qkv_gemm_kernel<<<dim3(MTOT / 128, ND3 / 128), dim3(256), 0, stream>>>(
      xb, Wt, bq, bk, bv, qkv);
  attn_kernel<<<dim3(S_ / 64, B_ * H_), dim3(256), 0, stream>>>(qkv, out);
}

// Round 2
// 143.972 us; speedup vs baseline: 1.2542x; 1.2542x over previous
//
#include <hip/hip_runtime.h>
#include <hip/hip_bf16.h>
#include <stdint.h>

// Problem constants
#define B_    2
#define S_    2048
#define H_    16
#define DH_   64
#define D_    1024
#define ND3   3072      // 3*D
#define MTOT  4096      // B*S

typedef __attribute__((ext_vector_type(8))) short bf16x8;
typedef __attribute__((ext_vector_type(4))) short bf16x4;
typedef __attribute__((ext_vector_type(4))) float f32x4;

__device__ inline short f2bs(float f) {
  __hip_bfloat16 h = __float2bfloat16(f);
  return *reinterpret_cast<short*>(&h);
}

__device__ inline void gl_lds16(const void* g, void* l) {
  __builtin_amdgcn_global_load_lds(
      (const __attribute__((address_space(1))) uint32_t*)g,
      (__attribute__((address_space(3))) uint32_t*)l, 16, 0, 0);
}

// ---------------------------------------------------------------- x -> bf16
__global__ __launch_bounds__(256) void xcast_kernel(const float* __restrict__ X,
                                                    short* __restrict__ Xb) {
  const int i = (blockIdx.x * 256 + threadIdx.x) * 4;
  float4 v = *reinterpret_cast<const float4*>(X + i);
  bf16x4 o;
  o[0] = f2bs(v.x); o[1] = f2bs(v.y); o[2] = f2bs(v.z); o[3] = f2bs(v.w);
  *reinterpret_cast<bf16x4*>(Xb + i) = o;
}

// ------------------------------------------- W[k][n] -> Wt[n][k] bf16 (x3)
__global__ __launch_bounds__(256) void wcast_kernel(const float* __restrict__ Wq,
                                                    const float* __restrict__ Wk,
                                                    const float* __restrict__ Wv,
                                                    short* __restrict__ Wt) {
  __shared__ float t[32][33];
  const float* W = blockIdx.z == 0 ? Wq : (blockIdx.z == 1 ? Wk : Wv);
  short* out = Wt + (size_t)blockIdx.z * (D_ * D_);
  const int x = threadIdx.x, y = threadIdx.y;
  const int n0 = blockIdx.x * 32, k0 = blockIdx.y * 32;
#pragma unroll
  for (int i = 0; i < 4; ++i)
    t[y + 8 * i][x] = W[(size_t)(k0 + y + 8 * i) * D_ + n0 + x];
  __syncthreads();
#pragma unroll
  for (int i = 0; i < 4; ++i)
    out[(size_t)(n0 + y + 8 * i) * D_ + k0 + x] = f2bs(t[x][y + 8 * i]);
}

// ---------------------------------------------------------------- QKV GEMM
// C[4096][3072] = Xb[4096][1024] @ W[1024][3072] (+bias, Q scaled by 0.125)
__global__ __launch_bounds__(256, 2) void qkv_gemm_kernel(
    const short* __restrict__ Xb, const short* __restrict__ Wt,
    const float* __restrict__ bq, const float* __restrict__ bk,
    const float* __restrict__ bv, short* __restrict__ QKV) {
  __shared__ short As[128 * 64];
  __shared__ short Bs[128 * 64];
  const int tid = threadIdx.x;
  const int lane = tid & 63, wid = tid >> 6;
  const int l15 = lane & 15, lg = lane >> 4;
  const int m0 = blockIdx.x * 128, n0 = blockIdx.y * 128;
  const int wr = (wid >> 1) * 64, wc = (wid & 1) * 64;

  f32x4 acc[4][4];
#pragma unroll
  for (int i = 0; i < 4; ++i)
#pragma unroll
    for (int j = 0; j < 4; ++j) acc[i][j] = (f32x4){0.f, 0.f, 0.f, 0.f};

  for (int k0 = 0; k0 < D_; k0 += 64) {
    __syncthreads();
#pragma unroll
    for (int it = 0; it < 4; ++it) {
      const int e = (it * 256 + tid) * 8;
      const int row = e >> 6, kk = e & 63;
      const int lb = (it * 256 + (tid & 192)) * 16;
      gl_lds16(Xb + (size_t)(m0 + row) * D_ + k0 + kk, (char*)As + lb);
      gl_lds16(Wt + (size_t)(n0 + row) * D_ + k0 + kk, (char*)Bs + lb);
    }
    __syncthreads();
#pragma unroll
    for (int ks = 0; ks < 2; ++ks) {
      bf16x8 a[4], b[4];
#pragma unroll
      for (int mt = 0; mt < 4; ++mt)
        a[mt] = *reinterpret_cast<const bf16x8*>(
            &As[(wr + mt * 16 + l15) * 64 + ks * 32 + lg * 8]);
#pragma unroll
      for (int nt = 0; nt < 4; ++nt)
        b[nt] = *reinterpret_cast<const bf16x8*>(
            &Bs[(wc + nt * 16 + l15) * 64 + ks * 32 + lg * 8]);
#pragma unroll
      for (int mt = 0; mt < 4; ++mt)
#pragma unroll
        for (int nt = 0; nt < 4; ++nt)
          acc[mt][nt] = __builtin_amdgcn_mfma_f32_16x16x32_bf16(
              a[mt], b[nt], acc[mt][nt], 0, 0, 0);
    }
  }
#pragma unroll
  for (int nt = 0; nt < 4; ++nt) {
    const int col = n0 + wc + nt * 16 + l15;
    float bias, qs;
    if (col < D_)            { bias = bq[col];          qs = 0.125f; }
    else if (col < 2 * D_)   { bias = bk[col - D_];     qs = 1.f; }
    else                     { bias = bv[col - 2 * D_]; qs = 1.f; }
#pragma unroll
    for (int mt = 0; mt < 4; ++mt)
#pragma unroll
      for (int r = 0; r < 4; ++r) {
        const int row = m0 + wr + mt * 16 + lg * 4 + r;
        QKV[(size_t)row * ND3 + col] = f2bs((acc[mt][nt][r] + bias) * qs);
      }
  }
}

// ----------------------------------------- V -> Vt[bh][dh][s] (head-major T)
__global__ __launch_bounds__(256) void vtrans_kernel(const short* __restrict__ QKV,
                                                     short* __restrict__ Vt) {
  __shared__ short t[64][72];
  const int st = blockIdx.x;   // s-tile of 64
  const int h  = blockIdx.y;
  const int b  = blockIdx.z;
  const int tid = threadIdx.x;
  const short* src = QKV + (size_t)(b * S_ + st * 64) * ND3 + 2 * D_ + h * DH_;
#pragma unroll
  for (int it = 0; it < 2; ++it) {
    const int g = it * 256 + tid;
    const int row = g >> 3, c = (g & 7) * 8;
    bf16x8 v = *reinterpret_cast<const bf16x8*>(src + (size_t)row * ND3 + c);
    *reinterpret_cast<bf16x8*>(&t[row][c]) = v;
  }
  __syncthreads();
  short* dst = Vt + (size_t)(b * H_ + h) * DH_ * S_ + st * 64;
#pragma unroll
  for (int it = 0; it < 2; ++it) {
    const int g = it * 256 + tid;
    const int dh = g >> 3, sc = (g & 7) * 8;
    bf16x8 v;
#pragma unroll
    for (int i = 0; i < 8; ++i) v[i] = t[sc + i][dh];
    *reinterpret_cast<bf16x8*>(dst + (size_t)dh * S_ + sc) = v;
  }
}

// ----------------------------------------------------------- flash attention
// grid (bh=32, qt=32) so each CU gets a MIX of qt (load balance).
// K/V double-buffered in linear LDS via global_load_lds with source-side
// XOR swizzle; reads use the same swizzle (rule #21: both-sides-or-neither).
__global__ __launch_bounds__(256, 2) void attn_kernel(
    const short* __restrict__ QKV, const short* __restrict__ Vtg,
    float* __restrict__ Out) {
  __shared__ short Ks[2][64 * 64];
  __shared__ short Vs[2][64 * 64];
  __shared__ short Ps[4][16][72];
  const int tid = threadIdx.x;
  const int lane = tid & 63, wid = tid >> 6;
  const int l15 = lane & 15, lg = lane >> 4;
  const int bh = blockIdx.x;
  const int qt = blockIdx.y;
  const int b = bh >> 4, h = bh & 15;
  const int q0 = qt * 64;
  const short* Qg = QKV + (size_t)b * S_ * ND3 + h * DH_;
  const short* Kg = QKV + (size_t)b * S_ * ND3 + D_ + h * DH_;
  const short* Vg = Vtg + (size_t)bh * DH_ * S_;

  // staging geometry: 64x64 bf16 tile = 512 chunks of 16B; thread t stages
  // linear chunks t and t+256. chunk g holds source chunk ((g&7) ^ (row&7)).
  const int srow = tid >> 3;                       // rows 0..31 (it0), +32 (it1)
  const int scol = ((tid & 7) ^ (srow & 7)) * 8;   // swizzled source chunk (shorts)

  // Q fragments in registers (pre-scaled by 1/8 in GEMM)
  bf16x8 qf[2];
  {
    const int qrow = q0 + wid * 16 + l15;
#pragma unroll
    for (int ks = 0; ks < 2; ++ks)
      qf[ks] = *reinterpret_cast<const bf16x8*>(Qg + (size_t)qrow * ND3 +
                                                ks * 32 + lg * 8);
  }

  f32x4 o[4];
#pragma unroll
  for (int i = 0; i < 4; ++i) o[i] = (f32x4){0.f, 0.f, 0.f, 0.f};
  float mrun[4] = {-1e30f, -1e30f, -1e30f, -1e30f};
  float lsum[4] = {0.f, 0.f, 0.f, 0.f};

#define STAGE(bufsel, kvt_)                                                  \
  {                                                                          \
    const int kv0_ = (kvt_) * 64;                                            \
    char* kb = (char*)Ks[bufsel] + (tid & 192) * 16;                         \
    char* vb = (char*)Vs[bufsel] + (tid & 192) * 16;                         \
    gl_lds16(Kg + (size_t)(kv0_ + srow) * ND3 + scol, kb);                   \
    gl_lds16(Kg + (size_t)(kv0_ + srow + 32) * ND3 + scol, kb + 4096);       \
    gl_lds16(Vg + (size_t)srow * S_ + kv0_ + scol, vb);                      \
    gl_lds16(Vg + (size_t)(srow + 32) * S_ + kv0_ + scol, vb + 4096);        \
  }

// swizzled fragment read: row = nt*16+l15, chunk = (ks*4+lg) ^ (row&7)
#define KFRAG(buf, nt, ks)                                                   \
  (*reinterpret_cast<const bf16x8*>(                                         \
      &Ks[buf][((nt) * 16 + l15) * 64 + (((((ks) * 4 + lg)) ^ (l15 & 7)) << 3)]))
#define VFRAG(buf, nt, ks)                                                   \
  (*reinterpret_cast<const bf16x8*>(                                         \
      &Vs[buf][((nt) * 16 + l15) * 64 + (((((ks) * 4 + lg)) ^ (l15 & 7)) << 3)]))

  STAGE(0, 0);
  __syncthreads();  // drains vmcnt -> buf0 ready
  int cur = 0;

  for (int kvt = 0; kvt <= qt; ++kvt) {
    const int kv0 = kvt * 64;
    if (kvt < qt) STAGE(cur ^ 1, kvt + 1);  // prefetch next tile (overlaps compute)

    // S = Q K^T  (Q pre-scaled)
    f32x4 s[4];
#pragma unroll
    for (int i = 0; i < 4; ++i) s[i] = (f32x4){0.f, 0.f, 0.f, 0.f};
#pragma unroll
    for (int ks = 0; ks < 2; ++ks)
#pragma unroll
      for (int nt = 0; nt < 4; ++nt)
        s[nt] = __builtin_amdgcn_mfma_f32_16x16x32_bf16(qf[ks],
                                                        KFRAG(cur, nt, ks),
                                                        s[nt], 0, 0, 0);
    if (kvt == qt) {  // causal mask on diagonal tile
#pragma unroll
      for (int nt = 0; nt < 4; ++nt) {
        const int col = kv0 + nt * 16 + l15;
#pragma unroll
        for (int r = 0; r < 4; ++r) {
          const int row = q0 + wid * 16 + lg * 4 + r;
          if (col > row) s[nt][r] = -1e30f;
        }
      }
    }
    // online softmax (rows live on 16-lane groups)
#pragma unroll
    for (int r = 0; r < 4; ++r) {
      float mx = fmaxf(fmaxf(s[0][r], s[1][r]), fmaxf(s[2][r], s[3][r]));
#pragma unroll
      for (int off = 1; off < 16; off <<= 1) mx = fmaxf(mx, __shfl_xor(mx, off));
      const float mnew = fmaxf(mrun[r], mx);
      const float sc = exp2f((mrun[r] - mnew) * 1.4426950408889634f);
      mrun[r] = mnew;
      float rowsum = 0.f;
#pragma unroll
      for (int nt = 0; nt < 4; ++nt) {
        float p = exp2f((s[nt][r] - mnew) * 1.4426950408889634f);
        s[nt][r] = p;
        rowsum += p;
      }
#pragma unroll
      for (int off = 1; off < 16; off <<= 1) rowsum += __shfl_xor(rowsum, off);
      lsum[r] = lsum[r] * sc + rowsum;
#pragma unroll
      for (int nt = 0; nt < 4; ++nt) o[nt][r] *= sc;
    }
    // P -> per-wave LDS (wave-local: DS in-order, no barrier needed)
#pragma unroll
    for (int nt = 0; nt < 4; ++nt)
#pragma unroll
      for (int r = 0; r < 4; ++r)
        Ps[wid][lg * 4 + r][nt * 16 + l15] = f2bs(s[nt][r]);
    // O += P V
#pragma unroll
    for (int ks = 0; ks < 2; ++ks) {
      bf16x8 af = *reinterpret_cast<const bf16x8*>(
          &Ps[wid][l15][ks * 32 + lg * 8]);
#pragma unroll
      for (int nt = 0; nt < 4; ++nt)
        o[nt] = __builtin_amdgcn_mfma_f32_16x16x32_bf16(af, VFRAG(cur, nt, ks),
                                                        o[nt], 0, 0, 0);
    }
    __syncthreads();  // drains vmcnt (prefetch landed) + all reads of cur done
    cur ^= 1;
  }
#undef STAGE
#undef KFRAG
#undef VFRAG

  // epilogue: O / lsum -> fp32 out [B,S,H,DH]
  const int orow0 = q0 + wid * 16 + lg * 4;
#pragma unroll
  for (int nt = 0; nt < 4; ++nt)
#pragma unroll
    for (int r = 0; r < 4; ++r)
      Out[((size_t)b * S_ + orow0 + r) * D_ + h * DH_ + nt * 16 + l15] =
          o[nt][r] / lsum[r];
}

// ---------------------------------------------------------------- launcher
extern "C" void kernel_launch(void* const* d_in, const int* in_sizes, int n_in,
                              void* d_out, int out_size, void* d_ws,
                              size_t ws_size, hipStream_t stream) {
  const float* x  = (const float*)d_in[0];
  const float* Wq = (const float*)d_in[1];
  const float* bq = (const float*)d_in[2];
  const float* Wk = (const float*)d_in[3];
  const float* bk = (const float*)d_in[4];
  const float* Wv = (const float*)d_in[5];
  const float* bv = (const float*)d_in[6];
  float* out = (float*)d_out;

  char* ws = (char*)d_ws;
  short* xb  = (short*)(ws);             //  8 MB: [4096][1024] bf16
  short* Wt  = (short*)(ws + 8388608);   //  6 MB: [3072][1024] bf16
  short* qkv = (short*)(ws + 14680064);  // 24 MB: [4096][3072] bf16
  short* Vt  = xb;                       //  8 MB: [32][64][2048] bf16 (reuses xb
                                         //  — xb is dead after the GEMM)

  xcast_kernel<<<dim3(MTOT * D_ / (256 * 4)), dim3(256), 0, stream>>>(x, xb);
  wcast_kernel<<<dim3(32, 32, 3), dim3(32, 8), 0, stream>>>(Wq, Wk, Wv, Wt);
  qkv_gemm_kernel<<<dim3(MTOT / 128, ND3 / 128), dim3(256), 0, stream>>>(
      xb, Wt, bq, bk, bv, qkv);
  vtrans_kernel<<<dim3(S_ / 64, H_, B_), dim3(256), 0, stream>>>(qkv, Vt);
  attn_kernel<<<dim3(B_ * H_, S_ / 64), dim3(256), 0, stream>>>(qkv, Vt, out);
}

// Round 3
// 102.103 us; speedup vs baseline: 1.7686x; 1.4101x over previous
//
#include <hip/hip_runtime.h>
#include <hip/hip_bf16.h>
#include <stdint.h>

// Problem constants
#define B_    2
#define S_    2048
#define H_    16
#define DH_   64
#define D_    1024
#define ND3   3072      // 3*D
#define MTOT  4096      // B*S
#define L2E   1.4426950408889634f

typedef __attribute__((ext_vector_type(8))) short bf16x8;
typedef __attribute__((ext_vector_type(4))) short bf16x4;
typedef __attribute__((ext_vector_type(4))) float f32x4;

__device__ inline short f2bs(float f) {
  __hip_bfloat16 h = __float2bfloat16(f);
  return *reinterpret_cast<short*>(&h);
}

__device__ inline void gl_lds16(const void* g, void* l) {
  __builtin_amdgcn_global_load_lds(
      (const __attribute__((address_space(1))) uint32_t*)g,
      (__attribute__((address_space(3))) uint32_t*)l, 16, 0, 0);
}

// ---------------------------------------------------------------- x -> bf16
__global__ __launch_bounds__(256) void xcast_kernel(const float* __restrict__ X,
                                                    short* __restrict__ Xb) {
  const int i = (blockIdx.x * 256 + threadIdx.x) * 4;
  float4 v = *reinterpret_cast<const float4*>(X + i);
  bf16x4 o;
  o[0] = f2bs(v.x); o[1] = f2bs(v.y); o[2] = f2bs(v.z); o[3] = f2bs(v.w);
  *reinterpret_cast<bf16x4*>(Xb + i) = o;
}

// ------------------------------------------- W[k][n] -> Wt[n][k] bf16 (x3)
__global__ __launch_bounds__(256) void wcast_kernel(const float* __restrict__ Wq,
                                                    const float* __restrict__ Wk,
                                                    const float* __restrict__ Wv,
                                                    short* __restrict__ Wt) {
  __shared__ float t[32][33];
  const float* W = blockIdx.z == 0 ? Wq : (blockIdx.z == 1 ? Wk : Wv);
  short* out = Wt + (size_t)blockIdx.z * (D_ * D_);
  const int x = threadIdx.x, y = threadIdx.y;
  const int n0 = blockIdx.x * 32, k0 = blockIdx.y * 32;
#pragma unroll
  for (int i = 0; i < 4; ++i)
    t[y + 8 * i][x] = W[(size_t)(k0 + y + 8 * i) * D_ + n0 + x];
  __syncthreads();
#pragma unroll
  for (int i = 0; i < 4; ++i)
    out[(size_t)(n0 + y + 8 * i) * D_ + k0 + x] = f2bs(t[x][y + 8 * i]);
}

// ---------------------------------------------------------------- QKV GEMM
// C[4096][3072] = Xb[4096][1024] @ W[1024][3072] (+bias, Q scaled by 0.125)
__global__ __launch_bounds__(256, 2) void qkv_gemm_kernel(
    const short* __restrict__ Xb, const short* __restrict__ Wt,
    const float* __restrict__ bq, const float* __restrict__ bk,
    const float* __restrict__ bv, short* __restrict__ QKV) {
  __shared__ short As[128 * 64];
  __shared__ short Bs[128 * 64];
  const int tid = threadIdx.x;
  const int lane = tid & 63, wid = tid >> 6;
  const int l15 = lane & 15, lg = lane >> 4;
  const int m0 = blockIdx.x * 128, n0 = blockIdx.y * 128;
  const int wr = (wid >> 1) * 64, wc = (wid & 1) * 64;

  f32x4 acc[4][4];
#pragma unroll
  for (int i = 0; i < 4; ++i)
#pragma unroll
    for (int j = 0; j < 4; ++j) acc[i][j] = (f32x4){0.f, 0.f, 0.f, 0.f};

  for (int k0 = 0; k0 < D_; k0 += 64) {
    __syncthreads();
#pragma unroll
    for (int it = 0; it < 4; ++it) {
      const int e = (it * 256 + tid) * 8;
      const int row = e >> 6, kk = e & 63;
      const int lb = (it * 256 + (tid & 192)) * 16;
      gl_lds16(Xb + (size_t)(m0 + row) * D_ + k0 + kk, (char*)As + lb);
      gl_lds16(Wt + (size_t)(n0 + row) * D_ + k0 + kk, (char*)Bs + lb);
    }
    __syncthreads();
#pragma unroll
    for (int ks = 0; ks < 2; ++ks) {
      bf16x8 a[4], b[4];
#pragma unroll
      for (int mt = 0; mt < 4; ++mt)
        a[mt] = *reinterpret_cast<const bf16x8*>(
            &As[(wr + mt * 16 + l15) * 64 + ks * 32 + lg * 8]);
#pragma unroll
      for (int nt = 0; nt < 4; ++nt)
        b[nt] = *reinterpret_cast<const bf16x8*>(
            &Bs[(wc + nt * 16 + l15) * 64 + ks * 32 + lg * 8]);
#pragma unroll
      for (int mt = 0; mt < 4; ++mt)
#pragma unroll
        for (int nt = 0; nt < 4; ++nt)
          acc[mt][nt] = __builtin_amdgcn_mfma_f32_16x16x32_bf16(
              a[mt], b[nt], acc[mt][nt], 0, 0, 0);
    }
  }
#pragma unroll
  for (int nt = 0; nt < 4; ++nt) {
    const int col = n0 + wc + nt * 16 + l15;
    float bias, qs;
    if (col < D_)            { bias = bq[col];          qs = 0.125f; }
    else if (col < 2 * D_)   { bias = bk[col - D_];     qs = 1.f; }
    else                     { bias = bv[col - 2 * D_]; qs = 1.f; }
#pragma unroll
    for (int mt = 0; mt < 4; ++mt)
#pragma unroll
      for (int r = 0; r < 4; ++r) {
        const int row = m0 + wr + mt * 16 + lg * 4 + r;
        QKV[(size_t)row * ND3 + col] = f2bs((acc[mt][nt][r] + bias) * qs);
      }
  }
}

// ----------------------------------------- V -> Vt[bh][dh][s] (head-major T)
__global__ __launch_bounds__(256) void vtrans_kernel(const short* __restrict__ QKV,
                                                     short* __restrict__ Vt) {
  __shared__ short t[64][72];
  const int st = blockIdx.x;
  const int h  = blockIdx.y;
  const int b  = blockIdx.z;
  const int tid = threadIdx.x;
  const short* src = QKV + (size_t)(b * S_ + st * 64) * ND3 + 2 * D_ + h * DH_;
#pragma unroll
  for (int it = 0; it < 2; ++it) {
    const int g = it * 256 + tid;
    const int row = g >> 3, c = (g & 7) * 8;
    bf16x8 v = *reinterpret_cast<const bf16x8*>(src + (size_t)row * ND3 + c);
    *reinterpret_cast<bf16x8*>(&t[row][c]) = v;
  }
  __syncthreads();
  short* dst = Vt + (size_t)(b * H_ + h) * DH_ * S_ + st * 64;
#pragma unroll
  for (int it = 0; it < 2; ++it) {
    const int g = it * 256 + tid;
    const int dh = g >> 3, sc = (g & 7) * 8;
    bf16x8 v;
#pragma unroll
    for (int i = 0; i < 8; ++i) v[i] = t[sc + i][dh];
    *reinterpret_cast<bf16x8*>(dst + (size_t)dh * S_ + sc) = v;
  }
}

// ----------------------------------------------------------- flash attention
// Swapped-operand layout: S^T = mfma(K,Q) puts a full q-row's kv-slice in ONE
// lane (q = lane&15) -> softmax is in-register + 4 shuffles/step (was 32).
// PV stays swapped (O^T = mfma(V,P)) so rescale/lsum are lane-local.
__global__ __launch_bounds__(256, 3) void attn_kernel(
    const short* __restrict__ QKV, const short* __restrict__ Vtg,
    float* __restrict__ Out) {
  __shared__ short Ks[2][64 * 64];
  __shared__ short Vs[2][64 * 64];
  __shared__ short Ps[4][16][72];
  const int tid = threadIdx.x;
  const int lane = tid & 63, wid = tid >> 6;
  const int l15 = lane & 15, lg = lane >> 4;
  const int bh = blockIdx.x;
  const int qt = (S_ / 64 - 1) - blockIdx.y;   // LPT: longest blocks first
  const int b = bh >> 4, h = bh & 15;
  const int q0 = qt * 64;
  const short* Qg = QKV + (size_t)b * S_ * ND3 + h * DH_;
  const short* Kg = QKV + (size_t)b * S_ * ND3 + D_ + h * DH_;
  const short* Vg = Vtg + (size_t)bh * DH_ * S_;

  // staging geometry: 64x64 bf16 tile = 512 chunks of 16B; thread t stages
  // linear chunks t and t+256; source chunk XOR-swizzled by row (rule #21).
  const int srow = tid >> 3;
  const int scol = ((tid & 7) ^ (srow & 7)) * 8;

  // Q fragment (B-operand rows = q): lane holds Q[q0+wid*16+l15][8*lg..+7]
  bf16x8 qf[2];
  {
    const int qrow = q0 + wid * 16 + l15;
#pragma unroll
    for (int ks = 0; ks < 2; ++ks)
      qf[ks] = *reinterpret_cast<const bf16x8*>(Qg + (size_t)qrow * ND3 +
                                                ks * 32 + lg * 8);
  }

  f32x4 o[4];   // o[nt][r] = O[q = q0+wid*16+l15][dh = nt*16+lg*4+r]
#pragma unroll
  for (int i = 0; i < 4; ++i) o[i] = (f32x4){0.f, 0.f, 0.f, 0.f};
  float mrun = -1e30f, lsum = 0.f;

#define STAGE(bufsel, kvt_)                                                  \
  {                                                                          \
    const int kv0_ = (kvt_) * 64;                                            \
    char* kb = (char*)Ks[bufsel] + (tid & 192) * 16;                         \
    char* vb = (char*)Vs[bufsel] + (tid & 192) * 16;                         \
    gl_lds16(Kg + (size_t)(kv0_ + srow) * ND3 + scol, kb);                   \
    gl_lds16(Kg + (size_t)(kv0_ + srow + 32) * ND3 + scol, kb + 4096);       \
    gl_lds16(Vg + (size_t)srow * S_ + kv0_ + scol, vb);                      \
    gl_lds16(Vg + (size_t)(srow + 32) * S_ + kv0_ + scol, vb + 4096);        \
  }

#define KFRAG(buf, nt, ks)                                                   \
  (*reinterpret_cast<const bf16x8*>(                                         \
      &Ks[buf][((nt) * 16 + l15) * 64 + (((((ks) * 4 + lg)) ^ (l15 & 7)) << 3)]))
#define VFRAG(buf, nt, ks)                                                   \
  (*reinterpret_cast<const bf16x8*>(                                         \
      &Vs[buf][((nt) * 16 + l15) * 64 + (((((ks) * 4 + lg)) ^ (l15 & 7)) << 3)]))

  STAGE(0, 0);
  __syncthreads();
  int cur = 0;

  for (int kvt = 0; kvt <= qt; ++kvt) {
    const int kv0 = kvt * 64;
    if (kvt < qt) STAGE(cur ^ 1, kvt + 1);  // prefetch overlaps compute

    // S^T = K Q^T : s[nt][r] = S[q = q0+wid*16+l15][kv = kv0+nt*16+lg*4+r]
    f32x4 s[4];
#pragma unroll
    for (int i = 0; i < 4; ++i) s[i] = (f32x4){0.f, 0.f, 0.f, 0.f};
#pragma unroll
    for (int ks = 0; ks < 2; ++ks)
#pragma unroll
      for (int nt = 0; nt < 4; ++nt)
        s[nt] = __builtin_amdgcn_mfma_f32_16x16x32_bf16(KFRAG(cur, nt, ks),
                                                        qf[ks], s[nt], 0, 0, 0);
    if (kvt == qt) {  // causal mask on diagonal tile
      const int q = q0 + wid * 16 + l15;
#pragma unroll
      for (int nt = 0; nt < 4; ++nt)
#pragma unroll
        for (int r = 0; r < 4; ++r)
          if (kv0 + nt * 16 + lg * 4 + r > q) s[nt][r] = -1e30f;
    }
    // online softmax: row q is lane-local (16 kv) + lg-group (xor 16/32)
    float mx = -1e30f;
#pragma unroll
    for (int nt = 0; nt < 4; ++nt)
#pragma unroll
      for (int r = 0; r < 4; ++r) mx = fmaxf(mx, s[nt][r]);
    mx = fmaxf(mx, __shfl_xor(mx, 16));
    mx = fmaxf(mx, __shfl_xor(mx, 32));
    const float mnew = fmaxf(mrun, mx);
    const float sc = exp2f((mrun - mnew) * L2E);
    mrun = mnew;
    float rowsum = 0.f;
#pragma unroll
    for (int nt = 0; nt < 4; ++nt)
#pragma unroll
      for (int r = 0; r < 4; ++r) {
        const float p = exp2f((s[nt][r] - mnew) * L2E);
        s[nt][r] = p;
        rowsum += p;
      }
    rowsum += __shfl_xor(rowsum, 16);
    rowsum += __shfl_xor(rowsum, 32);
    lsum = lsum * sc + rowsum;
#pragma unroll
    for (int nt = 0; nt < 4; ++nt)
#pragma unroll
      for (int r = 0; r < 4; ++r) o[nt][r] *= sc;

    // P -> per-wave LDS: lane writes P[q=l15][kv=nt*16+lg*4 .. +3] (b64 x4)
#pragma unroll
    for (int nt = 0; nt < 4; ++nt) {
      bf16x4 pk;
#pragma unroll
      for (int r = 0; r < 4; ++r) pk[r] = f2bs(s[nt][r]);
      *reinterpret_cast<bf16x4*>(&Ps[wid][l15][nt * 16 + lg * 4]) = pk;
    }
    // O^T += V P^T : o[nt] accumulates O[q=l15][dh=nt*16+lg*4+r]
#pragma unroll
    for (int ks = 0; ks < 2; ++ks) {
      bf16x8 af = *reinterpret_cast<const bf16x8*>(
          &Ps[wid][l15][ks * 32 + lg * 8]);   // P[q=l15][kv slice] (B-frag)
#pragma unroll
      for (int nt = 0; nt < 4; ++nt)
        o[nt] = __builtin_amdgcn_mfma_f32_16x16x32_bf16(VFRAG(cur, nt, ks), af,
                                                        o[nt], 0, 0, 0);
    }
    __syncthreads();  // prefetch landed + all reads of cur done
    cur ^= 1;
  }
#undef STAGE
#undef KFRAG
#undef VFRAG

  // epilogue: O / lsum -> fp32 out [B,S,H,DH]; float4 stores (r contiguous)
  const int q = q0 + wid * 16 + l15;
  const float inv = 1.f / lsum;
#pragma unroll
  for (int nt = 0; nt < 4; ++nt) {
    float4 v = {o[nt][0] * inv, o[nt][1] * inv, o[nt][2] * inv, o[nt][3] * inv};
    *reinterpret_cast<float4*>(
        &Out[((size_t)b * S_ + q) * D_ + h * DH_ + nt * 16 + lg * 4]) = v;
  }
}

// ---------------------------------------------------------------- launcher
extern "C" void kernel_launch(void* const* d_in, const int* in_sizes, int n_in,
                              void* d_out, int out_size, void* d_ws,
                              size_t ws_size, hipStream_t stream) {
  const float* x  = (const float*)d_in[0];
  const float* Wq = (const float*)d_in[1];
  const float* bq = (const float*)d_in[2];
  const float* Wk = (const float*)d_in[3];
  const float* bk = (const float*)d_in[4];
  const float* Wv = (const float*)d_in[5];
  const float* bv = (const float*)d_in[6];
  float* out = (float*)d_out;

  char* ws = (char*)d_ws;
  short* xb  = (short*)(ws);             //  8 MB: [4096][1024] bf16
  short* Wt  = (short*)(ws + 8388608);   //  6 MB: [3072][1024] bf16
  short* qkv = (short*)(ws + 14680064);  // 24 MB: [4096][3072] bf16
  short* Vt  = xb;                       //  8 MB: [32][64][2048] bf16 (xb dead)

  xcast_kernel<<<dim3(MTOT * D_ / (256 * 4)), dim3(256), 0, stream>>>(x, xb);
  wcast_kernel<<<dim3(32, 32, 3), dim3(32, 8), 0, stream>>>(Wq, Wk, Wv, Wt);
  qkv_gemm_kernel<<<dim3(MTOT / 128, ND3 / 128), dim3(256), 0, stream>>>(
      xb, Wt, bq, bk, bv, qkv);
  vtrans_kernel<<<dim3(S_ / 64, H_, B_), dim3(256), 0, stream>>>(qkv, Vt);
  attn_kernel<<<dim3(B_ * H_, S_ / 64), dim3(256), 0, stream>>>(qkv, Vt, out);
}

// Round 4
// 101.639 us; speedup vs baseline: 1.7766x; 1.0046x over previous
//
#include <hip/hip_runtime.h>
#include <hip/hip_bf16.h>
#include <stdint.h>

// Problem constants
#define B_    2
#define S_    2048
#define H_    16
#define DH_   64
#define D_    1024
#define ND3   3072      // 3*D
#define MTOT  4096      // B*S
#define L2E   1.4426950408889634f

typedef __attribute__((ext_vector_type(8))) short bf16x8;
typedef __attribute__((ext_vector_type(4))) short bf16x4;
typedef __attribute__((ext_vector_type(4))) float f32x4;

__device__ inline short f2bs(float f) {
  __hip_bfloat16 h = __float2bfloat16(f);
  return *reinterpret_cast<short*>(&h);
}

__device__ inline void gl_lds16(const void* g, void* l) {
  __builtin_amdgcn_global_load_lds(
      (const __attribute__((address_space(1))) uint32_t*)g,
      (__attribute__((address_space(3))) uint32_t*)l, 16, 0, 0);
}

// ---------------------------------------------------------------- x -> bf16
__global__ __launch_bounds__(256) void xcast_kernel(const float* __restrict__ X,
                                                    short* __restrict__ Xb) {
  const int i = (blockIdx.x * 256 + threadIdx.x) * 4;
  float4 v = *reinterpret_cast<const float4*>(X + i);
  bf16x4 o;
  o[0] = f2bs(v.x); o[1] = f2bs(v.y); o[2] = f2bs(v.z); o[3] = f2bs(v.w);
  *reinterpret_cast<bf16x4*>(Xb + i) = o;
}

// ------------------------------------------- W[k][n] -> Wt[n][k] bf16 (x3)
__global__ __launch_bounds__(256) void wcast_kernel(const float* __restrict__ Wq,
                                                    const float* __restrict__ Wk,
                                                    const float* __restrict__ Wv,
                                                    short* __restrict__ Wt) {
  __shared__ float t[32][33];
  const float* W = blockIdx.z == 0 ? Wq : (blockIdx.z == 1 ? Wk : Wv);
  short* out = Wt + (size_t)blockIdx.z * (D_ * D_);
  const int x = threadIdx.x, y = threadIdx.y;
  const int n0 = blockIdx.x * 32, k0 = blockIdx.y * 32;
#pragma unroll
  for (int i = 0; i < 4; ++i)
    t[y + 8 * i][x] = W[(size_t)(k0 + y + 8 * i) * D_ + n0 + x];
  __syncthreads();
#pragma unroll
  for (int i = 0; i < 4; ++i)
    out[(size_t)(n0 + y + 8 * i) * D_ + k0 + x] = f2bs(t[x][y + 8 * i]);
}

// ---------------------------------------------------------------- QKV GEMM
// C[4096][3072] = Xb[4096][1024] @ W[1024][3072] (+bias; Q scaled by
// 0.125*log2(e) so attention softmax can use exp2 directly).
__global__ __launch_bounds__(256, 3) void qkv_gemm_kernel(
    const short* __restrict__ Xb, const short* __restrict__ Wt,
    const float* __restrict__ bq, const float* __restrict__ bk,
    const float* __restrict__ bv, short* __restrict__ QKV) {
  __shared__ short As[128 * 64];
  __shared__ short Bs[128 * 64];
  const int tid = threadIdx.x;
  const int lane = tid & 63, wid = tid >> 6;
  const int l15 = lane & 15, lg = lane >> 4;
  const int m0 = blockIdx.x * 128, n0 = blockIdx.y * 128;
  const int wr = (wid >> 1) * 64, wc = (wid & 1) * 64;

  f32x4 acc[4][4];
#pragma unroll
  for (int i = 0; i < 4; ++i)
#pragma unroll
    for (int j = 0; j < 4; ++j) acc[i][j] = (f32x4){0.f, 0.f, 0.f, 0.f};

  for (int k0 = 0; k0 < D_; k0 += 64) {
    __syncthreads();
#pragma unroll
    for (int it = 0; it < 4; ++it) {
      const int e = (it * 256 + tid) * 8;
      const int row = e >> 6, kk = e & 63;
      const int lb = (it * 256 + (tid & 192)) * 16;
      gl_lds16(Xb + (size_t)(m0 + row) * D_ + k0 + kk, (char*)As + lb);
      gl_lds16(Wt + (size_t)(n0 + row) * D_ + k0 + kk, (char*)Bs + lb);
    }
    __syncthreads();
#pragma unroll
    for (int ks = 0; ks < 2; ++ks) {
      bf16x8 a[4], b[4];
#pragma unroll
      for (int mt = 0; mt < 4; ++mt)
        a[mt] = *reinterpret_cast<const bf16x8*>(
            &As[(wr + mt * 16 + l15) * 64 + ks * 32 + lg * 8]);
#pragma unroll
      for (int nt = 0; nt < 4; ++nt)
        b[nt] = *reinterpret_cast<const bf16x8*>(
            &Bs[(wc + nt * 16 + l15) * 64 + ks * 32 + lg * 8]);
#pragma unroll
      for (int mt = 0; mt < 4; ++mt)
#pragma unroll
        for (int nt = 0; nt < 4; ++nt)
          acc[mt][nt] = __builtin_amdgcn_mfma_f32_16x16x32_bf16(
              a[mt], b[nt], acc[mt][nt], 0, 0, 0);
    }
  }
#pragma unroll
  for (int nt = 0; nt < 4; ++nt) {
    const int col = n0 + wc + nt * 16 + l15;
    float bias, qs;
    if (col < D_)            { bias = bq[col];          qs = 0.125f * L2E; }
    else if (col < 2 * D_)   { bias = bk[col - D_];     qs = 1.f; }
    else                     { bias = bv[col - 2 * D_]; qs = 1.f; }
#pragma unroll
    for (int mt = 0; mt < 4; ++mt)
#pragma unroll
      for (int r = 0; r < 4; ++r) {
        const int row = m0 + wr + mt * 16 + lg * 4 + r;
        QKV[(size_t)row * ND3 + col] = f2bs((acc[mt][nt][r] + bias) * qs);
      }
  }
}

// ----------------------------------------- V -> Vt[bh][dh][s] (head-major T)
__global__ __launch_bounds__(256) void vtrans_kernel(const short* __restrict__ QKV,
                                                     short* __restrict__ Vt) {
  __shared__ short t[64][72];
  const int st = blockIdx.x;
  const int h  = blockIdx.y;
  const int b  = blockIdx.z;
  const int tid = threadIdx.x;
  const short* src = QKV + (size_t)(b * S_ + st * 64) * ND3 + 2 * D_ + h * DH_;
#pragma unroll
  for (int it = 0; it < 2; ++it) {
    const int g = it * 256 + tid;
    const int row = g >> 3, c = (g & 7) * 8;
    bf16x8 v = *reinterpret_cast<const bf16x8*>(src + (size_t)row * ND3 + c);
    *reinterpret_cast<bf16x8*>(&t[row][c]) = v;
  }
  __syncthreads();
  short* dst = Vt + (size_t)(b * H_ + h) * DH_ * S_ + st * 64;
#pragma unroll
  for (int it = 0; it < 2; ++it) {
    const int g = it * 256 + tid;
    const int dh = g >> 3, sc = (g & 7) * 8;
    bf16x8 v;
#pragma unroll
    for (int i = 0; i < 8; ++i) v[i] = t[sc + i][dh];
    *reinterpret_cast<bf16x8*>(dst + (size_t)dh * S_ + sc) = v;
  }
}

// ----------------------------------------------------------- flash attention
// Swapped operands throughout: S^T = mfma(K,Q) -> lane owns one q-row's kv
// slice; softmax fully in-register (exp2 directly, logits pre-scaled by
// log2e); PV via K=16 mfma consumes P straight from registers (no LDS
// round-trip). T13 defer-max skips the O rescale when max growth <= 8.
__global__ __launch_bounds__(256, 4) void attn_kernel(
    const short* __restrict__ QKV, const short* __restrict__ Vtg,
    float* __restrict__ Out) {
  __shared__ short Ks[2][64 * 64];
  __shared__ short Vs[2][64 * 64];
  const int tid = threadIdx.x;
  const int lane = tid & 63, wid = tid >> 6;
  const int l15 = lane & 15, lg = lane >> 4;
  const int bh = blockIdx.x;
  const int qt = (S_ / 64 - 1) - blockIdx.y;   // LPT: longest blocks first
  const int b = bh >> 4, h = bh & 15;
  const int q0 = qt * 64;
  const short* Qg = QKV + (size_t)b * S_ * ND3 + h * DH_;
  const short* Kg = QKV + (size_t)b * S_ * ND3 + D_ + h * DH_;
  const short* Vg = Vtg + (size_t)bh * DH_ * S_;

  // staging: 64x64 bf16 tile = 512 16B-chunks; thread t stages linear chunks
  // t and t+256; source chunk XOR-swizzled by row (rule #21).
  const int srow = tid >> 3;
  const int scol = ((tid & 7) ^ (srow & 7)) * 8;

  // Q fragment (B-operand): lane holds Q[q0+wid*16+l15][8*lg .. +7]
  bf16x8 qf[2];
  {
    const int qrow = q0 + wid * 16 + l15;
#pragma unroll
    for (int ks = 0; ks < 2; ++ks)
      qf[ks] = *reinterpret_cast<const bf16x8*>(Qg + (size_t)qrow * ND3 +
                                                ks * 32 + lg * 8);
  }

  f32x4 o[4];   // o[ntd][r] = O[q = q0+wid*16+l15][dh = ntd*16+lg*4+r]
#pragma unroll
  for (int i = 0; i < 4; ++i) o[i] = (f32x4){0.f, 0.f, 0.f, 0.f};
  float mrun = -1e30f, lsum = 0.f;

#define STAGE(bufsel, kvt_)                                                  \
  {                                                                          \
    const int kv0_ = (kvt_) * 64;                                            \
    char* kb = (char*)Ks[bufsel] + (tid & 192) * 16;                         \
    char* vb = (char*)Vs[bufsel] + (tid & 192) * 16;                         \
    gl_lds16(Kg + (size_t)(kv0_ + srow) * ND3 + scol, kb);                   \
    gl_lds16(Kg + (size_t)(kv0_ + srow + 32) * ND3 + scol, kb + 4096);       \
    gl_lds16(Vg + (size_t)srow * S_ + kv0_ + scol, vb);                      \
    gl_lds16(Vg + (size_t)(srow + 32) * S_ + kv0_ + scol, vb + 4096);        \
  }

// K A-frag (b128): row = nt*16+l15, chunk = (ks*4+lg) ^ (row&7)
#define KFRAG(buf, nt, ks)                                                   \
  (*reinterpret_cast<const bf16x8*>(                                         \
      &Ks[buf][((nt) * 16 + l15) * 64 + (((((ks) * 4 + lg)) ^ (l15 & 7)) << 3)]))
// V A-frag for K=16 mfma (b64): lane holds V^T[16*ntd+l15][16*ntk+4*lg .. +3]
#define VFRAG4(buf, ntd, ntk)                                                \
  (*reinterpret_cast<const bf16x4*>(                                         \
      (char*)Vs[buf] + ((16 * (ntd) + l15) * 128 +                           \
                        (((2 * (ntk) + (lg >> 1)) ^ (l15 & 7)) << 4) +       \
                        ((lg & 1) << 3))))

  STAGE(0, 0);
  __syncthreads();
  int cur = 0;

  for (int kvt = 0; kvt <= qt; ++kvt) {
    const int kv0 = kvt * 64;
    if (kvt < qt) STAGE(cur ^ 1, kvt + 1);  // prefetch overlaps compute

    // S^T = K Q^T : s[nt][r] = S[q][kv = kv0 + nt*16 + lg*4 + r]  (log2 units)
    f32x4 s[4];
#pragma unroll
    for (int i = 0; i < 4; ++i) s[i] = (f32x4){0.f, 0.f, 0.f, 0.f};
#pragma unroll
    for (int ks = 0; ks < 2; ++ks)
#pragma unroll
      for (int nt = 0; nt < 4; ++nt)
        s[nt] = __builtin_amdgcn_mfma_f32_16x16x32_bf16(KFRAG(cur, nt, ks),
                                                        qf[ks], s[nt], 0, 0, 0);
    if (kvt == qt) {  // causal mask on diagonal tile
      const int q = q0 + wid * 16 + l15;
#pragma unroll
      for (int nt = 0; nt < 4; ++nt)
#pragma unroll
        for (int r = 0; r < 4; ++r)
          if (kv0 + nt * 16 + lg * 4 + r > q) s[nt][r] = -1e30f;
    }
    // row max: 15 in-reg fmax + 2 cross-lane (row q lives on 4 lanes)
    float pmax = -1e30f;
#pragma unroll
    for (int nt = 0; nt < 4; ++nt)
#pragma unroll
      for (int r = 0; r < 4; ++r) pmax = fmaxf(pmax, s[nt][r]);
    pmax = fmaxf(pmax, __shfl_xor(pmax, 16));
    pmax = fmaxf(pmax, __shfl_xor(pmax, 32));
    // T13 defer-max: only rescale when some row's max grew by > 8 (log2)
    if (!__all(pmax <= mrun + 8.f)) {
      const float mnew = fmaxf(mrun, pmax);
      const float sc = exp2f(mrun - mnew);
      lsum *= sc;
#pragma unroll
      for (int nt = 0; nt < 4; ++nt)
#pragma unroll
        for (int r = 0; r < 4; ++r) o[nt][r] *= sc;
      mrun = mnew;
    }
    // P = exp2(s - m); pack bf16 in-register (PV B-frag layout == ownership)
    float rowsum = 0.f;
    bf16x4 pk[4];
#pragma unroll
    for (int nt = 0; nt < 4; ++nt)
#pragma unroll
      for (int r = 0; r < 4; ++r) {
        const float p = exp2f(s[nt][r] - mrun);
        rowsum += p;
        pk[nt][r] = f2bs(p);
      }
    rowsum += __shfl_xor(rowsum, 16);
    rowsum += __shfl_xor(rowsum, 32);
    lsum += rowsum;

    // O^T += V^T P^T via 16x16x16 mfma: B-frag = pk[ntk] direct from regs
#pragma unroll
    for (int ntk = 0; ntk < 4; ++ntk)
#pragma unroll
      for (int ntd = 0; ntd < 4; ++ntd)
        o[ntd] = __builtin_amdgcn_mfma_f32_16x16x16bf16_1k(
            VFRAG4(cur, ntd, ntk), pk[ntk], o[ntd], 0, 0, 0);

    __syncthreads();  // prefetch landed + all reads of cur done
    cur ^= 1;
  }
#undef STAGE
#undef KFRAG
#undef VFRAG4

  // epilogue: O / lsum -> fp32 out [B,S,H,DH]; float4 stores
  const int q = q0 + wid * 16 + l15;
  const float inv = 1.f / lsum;
#pragma unroll
  for (int nt = 0; nt < 4; ++nt) {
    float4 v = {o[nt][0] * inv, o[nt][1] * inv, o[nt][2] * inv, o[nt][3] * inv};
    *reinterpret_cast<float4*>(
        &Out[((size_t)b * S_ + q) * D_ + h * DH_ + nt * 16 + lg * 4]) = v;
  }
}

// ---------------------------------------------------------------- launcher
extern "C" void kernel_launch(void* const* d_in, const int* in_sizes, int n_in,
                              void* d_out, int out_size, void* d_ws,
                              size_t ws_size, hipStream_t stream) {
  const float* x  = (const float*)d_in[0];
  const float* Wq = (const float*)d_in[1];
  const float* bq = (const float*)d_in[2];
  const float* Wk = (const float*)d_in[3];
  const float* bk = (const float*)d_in[4];
  const float* Wv = (const float*)d_in[5];
  const float* bv = (const float*)d_in[6];
  float* out = (float*)d_out;

  char* ws = (char*)d_ws;
  short* xb  = (short*)(ws);             //  8 MB: [4096][1024] bf16
  short* Wt  = (short*)(ws + 8388608);   //  6 MB: [3072][1024] bf16
  short* qkv = (short*)(ws + 14680064);  // 24 MB: [4096][3072] bf16
  short* Vt  = xb;                       //  8 MB: [32][64][2048] bf16 (xb dead)

  xcast_kernel<<<dim3(MTOT * D_ / (256 * 4)), dim3(256), 0, stream>>>(x, xb);
  wcast_kernel<<<dim3(32, 32, 3), dim3(32, 8), 0, stream>>>(Wq, Wk, Wv, Wt);
  qkv_gemm_kernel<<<dim3(MTOT / 128, ND3 / 128), dim3(256), 0, stream>>>(
      xb, Wt, bq, bk, bv, qkv);
  vtrans_kernel<<<dim3(S_ / 64, H_, B_), dim3(256), 0, stream>>>(qkv, Vt);
  attn_kernel<<<dim3(B_ * H_, S_ / 64), dim3(256), 0, stream>>>(qkv, Vt, out);
}